// Round 6
// baseline (166.940 us; speedup 1.0000x reference)
//
#include <hip/hip_runtime.h>
#include <hip/hip_bf16.h>

#define HEADS 4
#define ODIM 64
#define HD 256          // HEADS*ODIM
#define NEG_SLOPE 0.2f
#define SPLITS 4

typedef __attribute__((ext_vector_type(8))) short bf16x8;
typedef __attribute__((ext_vector_type(4))) float floatx4;
typedef __attribute__((ext_vector_type(2))) float floatx2;

// ============ pack x and W -> bf16 hi/lo MFMA fragments (one launch) ============
__global__ __launch_bounds__(256) void pack_xw(const float* __restrict__ x,
                                               const float* __restrict__ W,
                                               __hip_bfloat16* __restrict__ xh,
                                               __hip_bfloat16* __restrict__ xl,
                                               __hip_bfloat16* __restrict__ wh,
                                               __hip_bfloat16* __restrict__ wl,
                                               int K, int nxb) {
    const int b = blockIdx.x;
    const int Kc = K >> 5;
    if (b < nxb) {
        const int g = b * 256 + threadIdx.x;
        const int lane = g & 63, frag = g >> 6;
        const int kc = frag % Kc, mc = frag / Kc;
        const int l16 = lane & 15, q = lane >> 4;
        const float* src = x + (size_t)(mc * 16 + l16) * K + kc * 32 + q * 8;
        const float4 v0 = *(const float4*)src;
        const float4 v1 = *(const float4*)(src + 4);
        const float vv[8] = {v0.x, v0.y, v0.z, v0.w, v1.x, v1.y, v1.z, v1.w};
        union { __hip_bfloat16 b[8]; bf16x8 v; } H, L;
        #pragma unroll
        for (int p = 0; p < 8; ++p) {
            H.b[p] = __float2bfloat16(vv[p]);
            L.b[p] = __float2bfloat16(vv[p] - __bfloat162float(H.b[p]));
        }
        *(bf16x8*)&xh[(size_t)frag * 512 + lane * 8] = H.v;
        *(bf16x8*)&xl[(size_t)frag * 512 + lane * 8] = L.v;
    } else {
        const int g = (b - nxb) * 256 + threadIdx.x;
        const int lane = g & 63, frag = g >> 6;
        const int kc = frag % Kc, nc = frag / Kc;
        const int l16 = lane & 15, q = lane >> 4;
        union { __hip_bfloat16 b[8]; bf16x8 v; } H, L;
        #pragma unroll
        for (int p = 0; p < 8; ++p) {
            const float w = W[(size_t)(kc * 32 + q * 8 + p) * HD + nc * 16 + l16];
            H.b[p] = __float2bfloat16(w);
            L.b[p] = __float2bfloat16(w - __bfloat162float(H.b[p]));
        }
        *(bf16x8*)&wh[(size_t)frag * 512 + lane * 8] = H.v;
        *(bf16x8*)&wl[(size_t)frag * 512 + lane * 8] = L.v;
    }
}

// ============ compress adj (n x n int) -> bit matrix (n x n/32 uint) ============
// wave w handles row i = w / (n/1024), j in [ (w % (n/1024))*1024, +1024 ): 16 ballots.
__global__ __launch_bounds__(256) void compress_adj(const int* __restrict__ adj,
                                                    unsigned int* __restrict__ bits, int n) {
    const int wid = (blockIdx.x * 256 + threadIdx.x) >> 6;
    const int lane = threadIdx.x & 63;
    const int nq = n >> 10;
    const int i = wid / nq;
    const int jb = (wid % nq) << 10;
    const int nw = n >> 5;
    #pragma unroll 4
    for (int jj = 0; jj < 16; ++jj) {
        const int j = jb + jj * 64 + lane;
        const unsigned long long m = __ballot(adj[(size_t)i * n + j] > 0);
        if (lane == 0) {
            uint2 u;
            u.x = (unsigned int)m;
            u.y = (unsigned int)(m >> 32);
            *(uint2*)&bits[(size_t)i * nw + ((jb + jj * 64) >> 5)] = u;
        }
    }
}

// ============ fused GEMM: h = x@W (hi/lo bf16 MFMA) + exp epilogue + B-frag pack of h ============
// block = 128 thr (2 waves, 16 rows each), grid (n/32, HEADS).
__global__ __launch_bounds__(128) void gemm_fused(
    const __hip_bfloat16* __restrict__ xh, const __hip_bfloat16* __restrict__ xl,
    const __hip_bfloat16* __restrict__ wh, const __hip_bfloat16* __restrict__ wl,
    const float* __restrict__ att, float2* __restrict__ esrc, float2* __restrict__ edst,
    __hip_bfloat16* __restrict__ hbB, int n, int K) {

    __shared__ __hip_bfloat16 T[64][40];

    const int tid = threadIdx.x, wave = tid >> 6, lane = tid & 63;
    const int q = lane >> 4, l16 = lane & 15;
    const int m0 = blockIdx.x * 32;
    const int head = blockIdx.y;
    const int Kc = K >> 5;
    const int mc = (m0 >> 4) + wave;

    floatx4 acc[4] = {{0.f,0.f,0.f,0.f},{0.f,0.f,0.f,0.f},{0.f,0.f,0.f,0.f},{0.f,0.f,0.f,0.f}};

    const __hip_bfloat16* Axh = xh + (size_t)mc * Kc * 512 + lane * 8;
    const __hip_bfloat16* Axl = xl + (size_t)mc * Kc * 512 + lane * 8;
    const __hip_bfloat16* Bwh = wh + lane * 8;
    const __hip_bfloat16* Bwl = wl + lane * 8;
    #pragma unroll 2
    for (int kc = 0; kc < Kc; ++kc) {
        const bf16x8 ah = *(const bf16x8*)(Axh + (size_t)kc * 512);
        const bf16x8 al = *(const bf16x8*)(Axl + (size_t)kc * 512);
        bf16x8 bh[4], bl[4];
        #pragma unroll
        for (int nt = 0; nt < 4; ++nt) {
            const size_t fo = (size_t)((head * 4 + nt) * Kc + kc) * 512;
            bh[nt] = *(const bf16x8*)(Bwh + fo);
            bl[nt] = *(const bf16x8*)(Bwl + fo);
        }
        #pragma unroll
        for (int nt = 0; nt < 4; ++nt)
            acc[nt] = __builtin_amdgcn_mfma_f32_16x16x32_bf16(ah, bh[nt], acc[nt], 0, 0, 0);
        #pragma unroll
        for (int nt = 0; nt < 4; ++nt)
            acc[nt] = __builtin_amdgcn_mfma_f32_16x16x32_bf16(ah, bl[nt], acc[nt], 0, 0, 0);
        #pragma unroll
        for (int nt = 0; nt < 4; ++nt)
            acc[nt] = __builtin_amdgcn_mfma_f32_16x16x32_bf16(al, bh[nt], acc[nt], 0, 0, 0);
    }

    // ---- exp epilogue: per-row e_src/e_dst sums -> esrc/edst arrays ----
    float as_v[4], ad_v[4];
    #pragma unroll
    for (int nt = 0; nt < 4; ++nt) {
        as_v[nt] = att[head * 2 * ODIM + nt * 16 + l16];
        ad_v[nt] = att[head * 2 * ODIM + ODIM + nt * 16 + l16];
    }
    #pragma unroll
    for (int r = 0; r < 4; ++r) {
        float ps = 0.f, pd = 0.f;
        #pragma unroll
        for (int nt = 0; nt < 4; ++nt) {
            ps = fmaf(acc[nt][r], as_v[nt], ps);
            pd = fmaf(acc[nt][r], ad_v[nt], pd);
        }
        #pragma unroll
        for (int m = 1; m <= 8; m <<= 1) {
            ps += __shfl_xor(ps, m, 64);
            pd += __shfl_xor(pd, m, 64);
        }
        if (l16 == 0) {
            const int i = m0 + wave * 16 + q * 4 + r;
            esrc[head * n + i] = make_float2(__expf(ps), __expf(NEG_SLOPE * ps));
            edst[head * n + i] = make_float2(__expf(pd), __expf(NEG_SLOPE * pd));
        }
    }

    // ---- write h tile transposed to LDS as bf16 ----
    #pragma unroll
    for (int nt = 0; nt < 4; ++nt) {
        union { __hip_bfloat16 b[4]; uint2 u; } pk;
        #pragma unroll
        for (int r = 0; r < 4; ++r) pk.b[r] = __float2bfloat16(acc[nt][r]);
        *(uint2*)&T[nt * 16 + l16][wave * 16 + q * 4] = pk.u;
    }
    __syncthreads();

    // ---- emit packed B-frags of h ----
    #pragma unroll
    for (int ffi = 0; ffi < 2; ++ffi) {
        const int f = wave + ffi * 2;   // nt
        const bf16x8 v = *(const bf16x8*)&T[f * 16 + l16][q * 8];
        const size_t frag = ((size_t)head * (n >> 5) + (m0 >> 5)) * 4 + f;
        *(bf16x8*)&hbB[frag * 512 + lane * 8] = v;
    }
}

// ============ aggregate v6: barrier-free, zero-LDS ============
// block: 4 waves (wave = head), i-tile 32 (mt=2), K split 4-way. Per 32-j step,
// each lane loads its MFMA operands directly: adjacency bits (L1 dword),
// dst-exps (L2 b128 x4), h B-frags (L2 b128 x4). No __syncthreads anywhere.
__global__ __launch_bounds__(256, 2) void aggregate(
    const unsigned int* __restrict__ bits, const float2* __restrict__ esrc,
    const float2* __restrict__ edst, const __hip_bfloat16* __restrict__ hbB,
    float* __restrict__ outsp, float* __restrict__ densp, int n, int KR) {

    const int tid = threadIdx.x;
    const int wave = tid >> 6, lane = tid & 63;
    const int q = lane >> 4, l16 = lane & 15;
    const int i0 = blockIdx.x * 32;
    const int K0 = blockIdx.y * KR;
    const int nw = n >> 5;

    // src-side exps for this lane's two rows (head = wave)
    floatx2 es12[2];
    #pragma unroll
    for (int mt = 0; mt < 2; ++mt) {
        const float2 e = esrc[wave * n + i0 + mt * 16 + l16];
        es12[mt][0] = e.x; es12[mt][1] = e.y;
    }

    // ones-column B-frag for MFMA-based denominator
    union { short s[8]; bf16x8 v; } bones;
    #pragma unroll
    for (int p = 0; p < 8; ++p) bones.s[p] = (l16 == 0) ? (short)0x3F80 : (short)0;

    floatx4 acc[2][4];
    floatx4 accd[2];
    #pragma unroll
    for (int mt = 0; mt < 2; ++mt) {
        accd[mt] = (floatx4){0.f, 0.f, 0.f, 0.f};
        #pragma unroll
        for (int nt = 0; nt < 4; ++nt) acc[mt][nt] = (floatx4){0.f, 0.f, 0.f, 0.f};
    }

    const unsigned int* brow0 = bits + (size_t)(i0 + l16) * nw + (K0 >> 5);
    const unsigned int* brow1 = bits + (size_t)(i0 + 16 + l16) * nw + (K0 >> 5);
    const float2* edp = edst + (size_t)wave * n + K0 + q * 8;   // 8 float2 per step
    const __hip_bfloat16* hb = hbB + ((size_t)wave * (n >> 5) + (K0 >> 5)) * 4 * 512 + lane * 8;

    const int NSTEP = KR >> 5;

    unsigned int cw0, cw1; float4 ced[4]; bf16x8 cbf[4];
    // load step 0
    cw0 = brow0[0]; cw1 = brow1[0];
    {
        const float4* ep = (const float4*)edp;
        ced[0] = ep[0]; ced[1] = ep[1]; ced[2] = ep[2]; ced[3] = ep[3];
        #pragma unroll
        for (int nt = 0; nt < 4; ++nt)
            cbf[nt] = *(const bf16x8*)&hb[(size_t)nt * 512];
    }

    for (int s = 0; s < NSTEP; ++s) {
        // ---- prefetch step s+1 (no barriers anywhere: stays in flight) ----
        unsigned int nw0, nw1; float4 ned[4]; bf16x8 nbf[4];
        const int sn = (s + 1 < NSTEP) ? s + 1 : s;
        nw0 = brow0[sn]; nw1 = brow1[sn];
        {
            const float4* ep = (const float4*)(edp + (size_t)sn * 32);
            ned[0] = ep[0]; ned[1] = ep[1]; ned[2] = ep[2]; ned[3] = ep[3];
            #pragma unroll
            for (int nt = 0; nt < 4; ++nt)
                nbf[nt] = *(const bf16x8*)&hb[((size_t)sn * 4 + nt) * 512];
        }

        // ---- compute step s ----
        #pragma unroll
        for (int mt = 0; mt < 2; ++mt) {
            const unsigned int bm = ((mt ? cw1 : cw0) >> (q * 8)) & 0xFFu;
            union { unsigned int u[4]; bf16x8 v; } af;
            #pragma unroll
            for (int p = 0; p < 4; ++p) {
                const float4 e = ced[p];     // {edz(2p), edw(2p), edz(2p+1), edw(2p+1)}
                floatx2 e0; e0[0] = e.x; e0[1] = e.y;
                floatx2 e1; e1[0] = e.z; e1[1] = e.w;
                const floatx2 pa = es12[mt] * e0;
                const floatx2 pb = es12[mt] * e1;
                const float wa = fmaxf(pa[0], pa[1]);   // leaky-relu in exp domain
                const float wb = fmaxf(pb[0], pb[1]);
                const unsigned int b2 = (bm >> (2 * p)) & 3u;
                const unsigned int mm = (b2 & 1u) * 0xFFFFu | (b2 >> 1) * 0xFFFF0000u;
                af.u[p] = __builtin_amdgcn_perm(__float_as_uint(wb), __float_as_uint(wa),
                                                0x07060302u) & mm;
            }
            #pragma unroll
            for (int nt = 0; nt < 4; ++nt)
                acc[mt][nt] = __builtin_amdgcn_mfma_f32_16x16x32_bf16(af.v, cbf[nt], acc[mt][nt], 0, 0, 0);
            accd[mt] = __builtin_amdgcn_mfma_f32_16x16x32_bf16(af.v, bones.v, accd[mt], 0, 0, 0);
        }

        cw0 = nw0; cw1 = nw1;
        #pragma unroll
        for (int p = 0; p < 4; ++p) ced[p] = ned[p];
        #pragma unroll
        for (int nt = 0; nt < 4; ++nt) cbf[nt] = nbf[nt];
    }

    // ---- epilogue: disjoint per-split writes ----
    const size_t sOut = (size_t)blockIdx.y * n * HD;
    #pragma unroll
    for (int mt = 0; mt < 2; ++mt)
        #pragma unroll
        for (int nt = 0; nt < 4; ++nt)
            #pragma unroll
            for (int r = 0; r < 4; ++r)
                outsp[sOut + (size_t)(i0 + mt * 16 + q * 4 + r) * HD + wave * ODIM + nt * 16 + l16] = acc[mt][nt][r];
    if (l16 == 0) {
        #pragma unroll
        for (int mt = 0; mt < 2; ++mt)
            #pragma unroll
            for (int r = 0; r < 4; ++r)
                densp[((size_t)blockIdx.y * n + i0 + mt * 16 + q * 4 + r) * HEADS + wave] = accd[mt][r];
    }
}

// ============ normalize: out = sum_s outsp / sum_s densp ============
__global__ __launch_bounds__(256) void normalize(const float* __restrict__ outsp,
                                                 const float* __restrict__ densp,
                                                 float* __restrict__ out, int n, int splits) {
    const int g = blockIdx.x * 256 + threadIdx.x;
    const int i = g >> 6;
    const int c4 = (g & 63) * 4;
    const int head = c4 >> 6;
    float den = 0.f;
    for (int s = 0; s < splits; ++s) den += densp[((size_t)s * n + i) * HEADS + head];
    float4 v = {0.f, 0.f, 0.f, 0.f};
    for (int s = 0; s < splits; ++s) {
        const float4 t = *(const float4*)&outsp[(size_t)s * n * HD + (size_t)i * HD + c4];
        v.x += t.x; v.y += t.y; v.z += t.z; v.w += t.w;
    }
    const float inv = 1.0f / den;
    v.x *= inv; v.y *= inv; v.z *= inv; v.w *= inv;
    *(float4*)&out[(size_t)i * HD + c4] = v;
}

extern "C" void kernel_launch(void* const* d_in, const int* in_sizes, int n_in,
                              void* d_out, int out_size, void* d_ws, size_t ws_size,
                              hipStream_t stream) {
    const float* x   = (const float*)d_in[0];
    const int*   adj = (const int*)d_in[1];
    const float* W   = (const float*)d_in[2];
    const float* att = (const float*)d_in[3];
    float* out = (float*)d_out;

    const int in_dim = in_sizes[2] / HD;   // 256
    const int n = in_sizes[0] / in_dim;    // 4096

    char* ws = (char*)d_ws;
    size_t off = 0;
    auto alloc = [&](size_t bytes) -> void* {
        void* p = ws + off; off += (bytes + 255) & ~(size_t)255; return p;
    };
    __hip_bfloat16* xh = (__hip_bfloat16*)alloc((size_t)n * in_dim * 2);
    __hip_bfloat16* xl = (__hip_bfloat16*)alloc((size_t)n * in_dim * 2);
    __hip_bfloat16* wh = (__hip_bfloat16*)alloc((size_t)in_dim * HD * 2);
    __hip_bfloat16* wl = (__hip_bfloat16*)alloc((size_t)in_dim * HD * 2);
    float2* esrc = (float2*)alloc((size_t)HEADS * n * 8);
    float2* edst = (float2*)alloc((size_t)HEADS * n * 8);
    __hip_bfloat16* hbB = (__hip_bfloat16*)alloc((size_t)n * HD * 2);
    unsigned int* bits = (unsigned int*)alloc((size_t)n * (n / 8));

    const size_t outB = (size_t)n * HD * 4, denB = (size_t)n * HEADS * 4;
    float* densp = (float*)alloc((size_t)SPLITS * denB);
    float* outsp = (float*)alloc((size_t)SPLITS * outB);

    const int nxb = (n / 16) * (in_dim / 32) * 64 / 256;
    const int nwb = (HD / 16) * (in_dim / 32) * 64 / 256;
    pack_xw<<<nxb + nwb, 256, 0, stream>>>(x, W, xh, xl, wh, wl, in_dim, nxb);
    compress_adj<<<(n * (n >> 10)) / 4, 256, 0, stream>>>(adj, bits, n);
    gemm_fused<<<dim3(n / 32, HEADS), 128, 0, stream>>>(xh, xl, wh, wl, att, esrc, edst, hbB, n, in_dim);
    aggregate<<<dim3(n / 32, SPLITS), 256, 0, stream>>>(bits, esrc, edst, hbB, outsp, densp, n, n / SPLITS);
    normalize<<<n * 64 / 256, 256, 0, stream>>>(outsp, densp, out, n, SPLITS);
}